// Round 2
// baseline (2376.993 us; speedup 1.0000x reference)
//
#include <hip/hip_runtime.h>
#include <hip/hip_bf16.h>
#include <stdint.h>

// ---------------------------------------------------------------------------
// Alignment_49735721287759: CLIP-style alignment head on MI355X (gfx950)
// Pipeline: L2-norm tokens -> factored scores -> top-16 -> gather ->
//           2-layer cross-attention transformer (2048 seqs x 17 tokens, D=512).
// q residual stream lives in d_out (f32). k stream stored bf16 (static across
// layers). Transformer is chunked over sequences with chunk size C chosen
// from ws_size (deterministic), floor ~67.5 MB scratch.
// ---------------------------------------------------------------------------

typedef __attribute__((ext_vector_type(8))) short short8;
typedef __attribute__((ext_vector_type(4))) float f32x4;

__device__ __forceinline__ float bf2f(short u) {
    return __uint_as_float(((uint32_t)(uint16_t)u) << 16);
}
__device__ __forceinline__ unsigned short f2bf(float f) {
    __hip_bfloat16 h = __float2bfloat16(f);
    return *reinterpret_cast<unsigned short*>(&h);
}

// ---------------- f32 -> bf16 convert (weights) ----------------
__global__ __launch_bounds__(256) void k_f2b(const float* __restrict__ in,
                                             unsigned short* __restrict__ out, int n) {
    for (int i = blockIdx.x * 256 + threadIdx.x; i < n; i += gridDim.x * 256)
        out[i] = f2bf(in[i]);
}

// ---------------- row L2 normalize (512-wide rows) ----------------
__global__ __launch_bounds__(256) void k_l2norm(const float* __restrict__ in,
                                                float* __restrict__ out) {
    size_t row = blockIdx.x;
    const float* x = in + row * 512;
    int t = threadIdx.x;
    float a0 = x[t], a1 = x[t + 256];
    float ss = a0 * a0 + a1 * a1;
#pragma unroll
    for (int off = 32; off; off >>= 1) ss += __shfl_xor(ss, off);
    __shared__ float s4[4];
    if ((t & 63) == 0) s4[t >> 6] = ss;
    __syncthreads();
    float tot = s4[0] + s4[1] + s4[2] + s4[3];
    float inv = 1.0f / sqrtf(tot);
    out[row * 512 + t] = a0 * inv;
    out[row * 512 + t + 256] = a1 * inv;
}

// ---------------- column sum over tokens (optionally masked) ----------------
__global__ __launch_bounds__(512) void k_colsum(const float* __restrict__ tok,
                                                const int* __restrict__ mask,
                                                float* __restrict__ out, int R) {
    int b = blockIdx.x;
    int d = threadIdx.x;  // 512 threads
    float acc = 0.f;
    for (int r = 0; r < R; r++) {
        float m = mask ? (float)mask[b * R + r] : 1.f;
        acc += m * tok[((size_t)b * R + r) * 512 + d];
    }
    out[b * 512 + d] = acc;
}

// ---------------- factored scores ----------------
// out[(i*32+j)*R + r] = dot(tok[tb][r], vec[vb]); swap selects batch mapping
__global__ __launch_bounds__(256) void k_scores(const float* __restrict__ tok,
                                                const float* __restrict__ vec,
                                                float* __restrict__ out, int R, int swap) {
    int bid = blockIdx.x;
    int i = bid >> 5, j = bid & 31;
    int tb = swap ? j : i;
    int vb = swap ? i : j;
    __shared__ float sv[512];
    for (int t = threadIdx.x; t < 512; t += 256) sv[t] = vec[vb * 512 + t];
    __syncthreads();
    int wv = threadIdx.x >> 6, lane = threadIdx.x & 63;
    for (int r = wv; r < R; r += 4) {
        const float* tr = tok + ((size_t)tb * R + r) * 512;
        float acc = 0.f;
#pragma unroll
        for (int c = 0; c < 8; c++) {
            int d = lane + c * 64;
            acc += tr[d] * sv[d];
        }
#pragma unroll
        for (int off = 32; off; off >>= 1) acc += __shfl_xor(acc, off);
        if (lane == 0) out[(size_t)bid * R + r] = acc;
    }
}

// ---------------- top-16 (values desc, ties -> lowest idx), output sorted asc
__global__ __launch_bounds__(64) void k_topk(const float* __restrict__ simg,
                                             const float* __restrict__ stxt,
                                             int* __restrict__ idx_i, int* __restrict__ idx_t) {
    int bid = blockIdx.x;  // 0..2047: first 1024 img (n=196), then txt (n=77)
    bool isimg = bid < 1024;
    int ij = isimg ? bid : bid - 1024;
    const float* s = isimg ? simg + (size_t)ij * 196 : stxt + (size_t)ij * 77;
    int n = isimg ? 196 : 77;
    int* out = (isimg ? idx_i : idx_t) + ij * 16;
    int lane = threadIdx.x;
    float v[4];
    int ids[4];
#pragma unroll
    for (int k = 0; k < 4; k++) {
        int id = lane + k * 64;
        ids[k] = id;
        v[k] = (id < n) ? s[id] : -3.0e38f;
    }
    __shared__ int sel[16];
    for (int r = 0; r < 16; r++) {
        float bv = v[0];
        int bi = ids[0];
#pragma unroll
        for (int k = 1; k < 4; k++)
            if (v[k] > bv) { bv = v[k]; bi = ids[k]; }
#pragma unroll
        for (int off = 32; off; off >>= 1) {
            float ov = __shfl_xor(bv, off);
            int oi = __shfl_xor(bi, off);
            if (ov > bv || (ov == bv && oi < bi)) { bv = ov; bi = oi; }
        }
        if (lane == 0) sel[r] = bi;
#pragma unroll
        for (int k = 0; k < 4; k++)
            if (ids[k] == bi) v[k] = -3.0e38f;
    }
    if (lane == 0) {
        for (int a = 1; a < 16; a++) {
            int key = sel[a];
            int b = a - 1;
            while (b >= 0 && sel[b] > key) { sel[b + 1] = sel[b]; b--; }
            sel[b + 1] = key;
        }
        for (int a = 0; a < 16; a++) out[a] = sel[a];
    }
}

// ---------------- gather q (f32, into d_out) / k (bf16) token rows ----------
__global__ __launch_bounds__(128) void k_gather(const float* __restrict__ img_n,
                                                const float* __restrict__ txt_n,
                                                const float* __restrict__ img_feat,
                                                const float* __restrict__ txt_feat,
                                                const float* __restrict__ img_cls,
                                                const float* __restrict__ txt_cls,
                                                const int* __restrict__ idx_i,
                                                const int* __restrict__ idx_t,
                                                float* __restrict__ q,
                                                unsigned short* __restrict__ k) {
    int rid = blockIdx.x;  // 0..69631
    int buf = rid / 34816;
    int rem = rid % 34816;
    int seq = rem / 17, t = rem % 17;
    int c = seq >> 10, ij = seq & 1023, i = ij >> 5, j = ij & 31;
    const float* src;
    if (buf == 0) {  // q tensor
        if (c == 0)
            src = (t == 0) ? img_cls : img_n + ((size_t)i * 196 + idx_i[ij * 16 + t - 1]) * 512;
        else
            src = (t == 0) ? txt_cls : txt_n + ((size_t)j * 77 + idx_t[ij * 16 + t - 1]) * 512;
    } else {  // k tensor
        if (c == 0)
            src = (t == 0) ? (txt_feat + (size_t)j * 512)
                           : txt_n + ((size_t)j * 77 + idx_t[ij * 16 + t - 1]) * 512;
        else
            src = (t == 0) ? (img_feat + (size_t)i * 512)
                           : img_n + ((size_t)i * 196 + idx_i[ij * 16 + t - 1]) * 512;
    }
    float4 v = ((const float4*)src)[threadIdx.x];
    size_t row = (size_t)seq * 17 + t;
    if (buf == 0) {
        ((float4*)(q + row * 512))[threadIdx.x] = v;
    } else {
        ushort4 o;
        o.x = f2bf(v.x); o.y = f2bf(v.y); o.z = f2bf(v.z); o.w = f2bf(v.w);
        ((ushort4*)(k + row * 512))[threadIdx.x] = o;
    }
}

// ---------------- LayerNorm 512-wide -> bf16 out; BF: input bf16 else f32 ----
template <int BF>
__global__ __launch_bounds__(256) void k_ln(const void* __restrict__ xv,
                                            const float* __restrict__ w,
                                            const float* __restrict__ b,
                                            unsigned short* __restrict__ out) {
    size_t row = blockIdx.x;
    int t = threadIdx.x;
    float a0, a1;
    if (BF) {
        const short* xr = (const short*)xv + row * 512;
        a0 = bf2f(xr[t]);
        a1 = bf2f(xr[t + 256]);
    } else {
        const float* xr = (const float*)xv + row * 512;
        a0 = xr[t];
        a1 = xr[t + 256];
    }
    float s = a0 + a1, qq = a0 * a0 + a1 * a1;
#pragma unroll
    for (int off = 32; off; off >>= 1) {
        s += __shfl_xor(s, off);
        qq += __shfl_xor(qq, off);
    }
    __shared__ float s4[4], q4[4];
    if ((t & 63) == 0) { s4[t >> 6] = s; q4[t >> 6] = qq; }
    __syncthreads();
    s = s4[0] + s4[1] + s4[2] + s4[3];
    qq = q4[0] + q4[1] + q4[2] + q4[3];
    float mean = s * (1.f / 512.f);
    float var = qq * (1.f / 512.f) - mean * mean;
    float rs = rsqrtf(var + 1e-5f);
    out[row * 512 + t] = f2bf((a0 - mean) * rs * w[t] + b[t]);
    out[row * 512 + t + 256] = f2bf((a1 - mean) * rs * w[t + 256] + b[t + 256]);
}

// ---------------- bf16 MFMA GEMM: C(MxN) = A(MxK) @ W(NxK)^T + bias ----------
// MODE 0: C bf16;  MODE 1: C bf16 = gelu(val);  MODE 2: C f32 += val (residual)
// block 256 = 4 waves (2x2), wave tile 64x64, frags 16x16x32. M,N % 128 == 0.
template <int MODE>
__global__ __launch_bounds__(256) void k_gemm(const unsigned short* __restrict__ A,
                                              const unsigned short* __restrict__ W,
                                              const float* __restrict__ bias,
                                              void* __restrict__ Cv, int K, int N, int ldc) {
    int lane = threadIdx.x & 63;
    int w = threadIdx.x >> 6;
    int wm = w >> 1, wn = w & 1;
    int r16 = lane & 15, g = lane >> 4;
    size_t rowA = (size_t)blockIdx.x * 128 + wm * 64 + r16;
    size_t colB = (size_t)blockIdx.y * 128 + wn * 64 + r16;
    const short* Ap = (const short*)A + rowA * K + g * 8;
    const short* Wp = (const short*)W + colB * K + g * 8;
    f32x4 acc[4][4] = {};
    for (int kk = 0; kk < K; kk += 32) {
        short8 a[4], b[4];
#pragma unroll
        for (int m = 0; m < 4; m++) a[m] = *(const short8*)(Ap + (size_t)m * 16 * K + kk);
#pragma unroll
        for (int n = 0; n < 4; n++) b[n] = *(const short8*)(Wp + (size_t)n * 16 * K + kk);
#pragma unroll
        for (int m = 0; m < 4; m++)
#pragma unroll
            for (int n = 0; n < 4; n++)
                acc[m][n] = __builtin_amdgcn_mfma_f32_16x16x32_bf16(a[m], b[n], acc[m][n], 0, 0, 0);
    }
    size_t rbase = (size_t)blockIdx.x * 128 + wm * 64 + g * 4;
    size_t cbase = (size_t)blockIdx.y * 128 + wn * 64 + r16;
#pragma unroll
    for (int m = 0; m < 4; m++)
#pragma unroll
        for (int n = 0; n < 4; n++) {
            size_t col = cbase + n * 16;
            float bv = bias ? bias[col] : 0.f;
#pragma unroll
            for (int r = 0; r < 4; r++) {
                size_t row = rbase + m * 16 + r;
                float val = acc[m][n][r] + bv;
                if (MODE == 0) {
                    ((unsigned short*)Cv)[row * ldc + col] = f2bf(val);
                } else if (MODE == 1) {
                    float gv = val / (1.f + __expf(-1.702f * val));
                    ((unsigned short*)Cv)[row * ldc + col] = f2bf(gv);
                } else {
                    ((float*)Cv)[row * ldc + col] += val;
                }
            }
        }
}

// ---------------- attention: per-seq block (512 thr = 8 waves = 8 heads) ------
// Q rows (17x512 bf16, ld 512); KV rows (17x1024 bf16: K cols 0..511, V 512..1023)
__global__ __launch_bounds__(512) void k_attn(const unsigned short* __restrict__ Qm,
                                              const unsigned short* __restrict__ KVm,
                                              unsigned short* __restrict__ Om) {
    __shared__ __align__(16) short sAll[3 * 17 * 520];
    __shared__ float sP[8 * 17 * 17];
    int seq = blockIdx.x;
    size_t tb = (size_t)seq * 17;
    for (int c = threadIdx.x; c < 3264; c += 512) {
        int mat = c / 1088, rem = c % 1088, row = rem >> 6, ch = rem & 63;
        const short8* src;
        if (mat == 0)
            src = (const short8*)(Qm + (tb + row) * 512 + ch * 8);
        else if (mat == 1)
            src = (const short8*)(KVm + (tb + row) * 1024 + ch * 8);
        else
            src = (const short8*)(KVm + (tb + row) * 1024 + 512 + ch * 8);
        *(short8*)&sAll[mat * (17 * 520) + row * 520 + ch * 8] = *src;
    }
    __syncthreads();
    int h = threadIdx.x >> 6, lane = threadIdx.x & 63;
    const short* sQ = sAll;
    const short* sK = sAll + 17 * 520;
    const short* sV = sAll + 2 * 17 * 520;
    int jj = lane < 17 ? lane : 0;
    for (int i = 0; i < 17; i++) {
        float acc = 0.f;
#pragma unroll
        for (int c = 0; c < 8; c++) {
            short8 q8 = *(const short8*)&sQ[i * 520 + h * 64 + c * 8];
            short8 k8 = *(const short8*)&sK[jj * 520 + h * 64 + c * 8];
#pragma unroll
            for (int e = 0; e < 8; e++) acc += bf2f(q8[e]) * bf2f(k8[e]);
        }
        float sc = (lane < 17) ? acc * 0.125f : -1e30f;
        float m = sc;
#pragma unroll
        for (int off = 32; off; off >>= 1) m = fmaxf(m, __shfl_xor(m, off));
        float p = (lane < 17) ? __expf(sc - m) : 0.f;
        float sum = p;
#pragma unroll
        for (int off = 32; off; off >>= 1) sum += __shfl_xor(sum, off);
        if (lane < 17) sP[(h * 17 + i) * 17 + lane] = p / sum;
    }
    for (int i = 0; i < 17; i++) {
        float o = 0.f;
#pragma unroll
        for (int t = 0; t < 17; t++)
            o += sP[(h * 17 + i) * 17 + t] * bf2f(sV[t * 520 + h * 64 + lane]);
        Om[(tb + i) * 512 + h * 64 + lane] = f2bf(o);
    }
}

// ---------------------------------------------------------------------------
extern "C" void kernel_launch(void* const* d_in, const int* in_sizes, int n_in,
                              void* d_out, int out_size, void* d_ws, size_t ws_size,
                              hipStream_t stream) {
    const float* image_feature = (const float*)d_in[0];
    const float* image_tokens = (const float*)d_in[1];
    const float* text_feature = (const float*)d_in[2];
    const float* text_tokens = (const float*)d_in[3];
    const int* atte_mask = (const int*)d_in[4];
    const float* img_cls = (const float*)d_in[5];
    const float* txt_cls = (const float*)d_in[6];
    const float* in_proj_w = (const float*)d_in[7];
    const float* in_proj_b = (const float*)d_in[8];
    const float* out_w = (const float*)d_in[9];
    const float* out_b = (const float*)d_in[10];
    const float* ln1_w = (const float*)d_in[11];
    const float* ln1_b = (const float*)d_in[12];
    const float* ln2_w = (const float*)d_in[13];
    const float* ln2_b = (const float*)d_in[14];
    const float* ln3_w = (const float*)d_in[15];
    const float* ln3_b = (const float*)d_in[16];
    const float* fc_w = (const float*)d_in[17];
    const float* fc_b = (const float*)d_in[18];
    const float* proj_w = (const float*)d_in[19];
    const float* proj_b = (const float*)d_in[20];

    // ---- workspace layout (adaptive) ----
    // [0, 12,582,912)            bf16 weights (persistent)
    // [OFF_K, +35,651,584)       k stream bf16 (persistent)
    // [OFF_CH, +87040*C)         chunk region: qn (17408*C) | qkv/atto (69632*C)
    //   early-stage overlay at OFF_CH (19,271,680 B; dead before transformer):
    //   img_n | txt_n | isum | tmask | simg | stxt | idx_i | idx_t
    char* ws = (char*)d_ws;
    const size_t OFF_K = 12582912;
    const size_t OFF_CH = OFF_K + 35651584;  // 48,234,496
    size_t avail = ws_size > OFF_CH ? ws_size - OFF_CH : 0;
    int C = 2048;  // seqs per chunk
    while (C > 128 && (size_t)87040 * C > avail) C >>= 1;
    // floor: OFF_CH + max(19.27MB early, 87040*C). If ws is below even that,
    // we run anyway (a fault is more diagnosable than a silent no-op).
    int nch = 2048 / C;

    unsigned short* wbf = (unsigned short*)ws;
    unsigned short* w_inproj = wbf;                // 2*1536*512 elems
    unsigned short* w_outp = wbf + 1572864;        // 2*512*512
    unsigned short* w_fc = wbf + 2097152;          // 2*2048*512
    unsigned short* w_proj = wbf + 4194304;        // 2*512*2048
    unsigned short* kstream = (unsigned short*)(ws + OFF_K);
    char* chreg = ws + OFF_CH;
    // early overlay
    float* img_n = (float*)(chreg + 0);            // 12,845,056
    float* txt_n = (float*)(chreg + 12845056);     //  5,046,272
    float* isum = (float*)(chreg + 17891328);      //     65,536
    float* tmask = (float*)(chreg + 17956864);     //     65,536
    float* simg = (float*)(chreg + 18022400);      //    802,816
    float* stxt = (float*)(chreg + 18825216);      //    315,392
    int* idx_i = (int*)(chreg + 19140608);         //     65,536
    int* idx_t = (int*)(chreg + 19206144);         //     65,536
    // chunk-time pointers
    unsigned short* qn = (unsigned short*)chreg;                      // 17408*C B
    unsigned short* qkvQ = (unsigned short*)(chreg + (size_t)17408 * C);
    unsigned short* qkvKV = (unsigned short*)(chreg + (size_t)34816 * C);
    unsigned short* atto = (unsigned short*)(chreg + (size_t)69632 * C);
    unsigned short* hbuf = qkvQ;  // 69632*C B, overlays qkvQ+qkvKV+atto
    float* q = (float*)d_out;

    // weights -> bf16
    k_f2b<<<1024, 256, 0, stream>>>(in_proj_w, w_inproj, 1572864);
    k_f2b<<<1024, 256, 0, stream>>>(out_w, w_outp, 524288);
    k_f2b<<<1024, 256, 0, stream>>>(fc_w, w_fc, 2097152);
    k_f2b<<<1024, 256, 0, stream>>>(proj_w, w_proj, 2097152);

    // token normalize
    k_l2norm<<<6272, 256, 0, stream>>>(image_tokens, img_n);
    k_l2norm<<<2464, 256, 0, stream>>>(text_tokens, txt_n);

    // factored score vectors
    k_colsum<<<32, 512, 0, stream>>>(img_n, nullptr, isum, 196);
    k_colsum<<<32, 512, 0, stream>>>(txt_n, atte_mask, tmask, 77);

    // scores + top-k + gather (q -> d_out f32, k -> bf16)
    k_scores<<<1024, 256, 0, stream>>>(img_n, tmask, simg, 196, 0);
    k_scores<<<1024, 256, 0, stream>>>(txt_n, isum, stxt, 77, 1);
    k_topk<<<2048, 64, 0, stream>>>(simg, stxt, idx_i, idx_t);
    k_gather<<<69632, 128, 0, stream>>>(img_n, txt_n, image_feature, text_feature,
                                        img_cls, txt_cls, idx_i, idx_t, q, kstream);

    // 2-layer cross-attention transformer, chunked over sequences
    for (int ch = 0; ch < nch; ch++) {
        size_t r0 = (size_t)ch * C * 17;
        float* qc = q + r0 * 512;
        const unsigned short* kc = kstream + r0 * 512;
        int rowsC = 17 * C;
        int gx = rowsC / 128;  // 17*C % 128 == 0 for C in {128..2048}
        for (int l = 0; l < 2; l++) {
            const unsigned short* Wq = w_inproj + (size_t)l * 786432;
            const unsigned short* Wkv = Wq + 262144;
            const float* bq = in_proj_b + l * 1536;
            const float* bkv = bq + 512;
            k_ln<0><<<rowsC, 256, 0, stream>>>(qc, ln1_w + l * 512, ln1_b + l * 512, qn);
            k_gemm<0><<<dim3(gx, 4), 256, 0, stream>>>(qn, Wq, bq, qkvQ, 512, 512, 512);
            k_ln<1><<<rowsC, 256, 0, stream>>>(kc, ln2_w + l * 512, ln2_b + l * 512, qn);
            k_gemm<0><<<dim3(gx, 8), 256, 0, stream>>>(qn, Wkv, bkv, qkvKV, 512, 1024, 1024);
            k_attn<<<C, 512, 0, stream>>>(qkvQ, qkvKV, atto);
            k_gemm<2><<<dim3(gx, 4), 256, 0, stream>>>(atto, w_outp + (size_t)l * 262144,
                                                       out_b + l * 512, qc, 512, 512, 512);
            k_ln<0><<<rowsC, 256, 0, stream>>>(qc, ln3_w + l * 512, ln3_b + l * 512, qn);
            k_gemm<1><<<dim3(gx, 16), 256, 0, stream>>>(qn, w_fc + (size_t)l * 1048576,
                                                        fc_b + l * 2048, hbuf, 512, 2048, 2048);
            k_gemm<2><<<dim3(gx, 4), 256, 0, stream>>>(hbuf, w_proj + (size_t)l * 1048576,
                                                       proj_b + l * 512, qc, 2048, 512, 512);
        }
    }
}

// Round 3
// 1684.765 us; speedup vs baseline: 1.4109x; 1.4109x over previous
//
#include <hip/hip_runtime.h>
#include <hip/hip_bf16.h>
#include <stdint.h>

// ---------------------------------------------------------------------------
// Alignment_49735721287759: CLIP-style alignment head on MI355X (gfx950)
// Round 3: LDS-staged MFMA GEMM (m97 structure: 128x128 tile, BK=64,
// global_load_lds width-16, 2 barriers/K-step) + bijective XCD swizzle.
// ---------------------------------------------------------------------------

typedef __attribute__((ext_vector_type(8))) short short8;
typedef __attribute__((ext_vector_type(4))) float f32x4;

__device__ __forceinline__ float bf2f(short u) {
    return __uint_as_float(((uint32_t)(uint16_t)u) << 16);
}
__device__ __forceinline__ unsigned short f2bf(float f) {
    __hip_bfloat16 h = __float2bfloat16(f);
    return *reinterpret_cast<unsigned short*>(&h);
}
__device__ __forceinline__ void gload16(const void* g, void* l) {
    __builtin_amdgcn_global_load_lds(
        (const __attribute__((address_space(1))) unsigned int*)g,
        (__attribute__((address_space(3))) unsigned int*)l, 16, 0, 0);
}

// ---------------- f32 -> bf16 convert (weights) ----------------
__global__ __launch_bounds__(256) void k_f2b(const float* __restrict__ in,
                                             unsigned short* __restrict__ out, int n) {
    for (int i = blockIdx.x * 256 + threadIdx.x; i < n; i += gridDim.x * 256)
        out[i] = f2bf(in[i]);
}

// ---------------- row L2 normalize (512-wide rows) ----------------
__global__ __launch_bounds__(256) void k_l2norm(const float* __restrict__ in,
                                                float* __restrict__ out) {
    size_t row = blockIdx.x;
    const float* x = in + row * 512;
    int t = threadIdx.x;
    float a0 = x[t], a1 = x[t + 256];
    float ss = a0 * a0 + a1 * a1;
#pragma unroll
    for (int off = 32; off; off >>= 1) ss += __shfl_xor(ss, off);
    __shared__ float s4[4];
    if ((t & 63) == 0) s4[t >> 6] = ss;
    __syncthreads();
    float tot = s4[0] + s4[1] + s4[2] + s4[3];
    float inv = 1.0f / sqrtf(tot);
    out[row * 512 + t] = a0 * inv;
    out[row * 512 + t + 256] = a1 * inv;
}

// ---------------- column sum over tokens (optionally masked) ----------------
__global__ __launch_bounds__(512) void k_colsum(const float* __restrict__ tok,
                                                const int* __restrict__ mask,
                                                float* __restrict__ out, int R) {
    int b = blockIdx.x;
    int d = threadIdx.x;  // 512 threads
    float acc = 0.f;
    for (int r = 0; r < R; r++) {
        float m = mask ? (float)mask[b * R + r] : 1.f;
        acc += m * tok[((size_t)b * R + r) * 512 + d];
    }
    out[b * 512 + d] = acc;
}

// ---------------- factored scores ----------------
__global__ __launch_bounds__(256) void k_scores(const float* __restrict__ tok,
                                                const float* __restrict__ vec,
                                                float* __restrict__ out, int R, int swap) {
    int bid = blockIdx.x;
    int i = bid >> 5, j = bid & 31;
    int tb = swap ? j : i;
    int vb = swap ? i : j;
    __shared__ float sv[512];
    for (int t = threadIdx.x; t < 512; t += 256) sv[t] = vec[vb * 512 + t];
    __syncthreads();
    int wv = threadIdx.x >> 6, lane = threadIdx.x & 63;
    for (int r = wv; r < R; r += 4) {
        const float* tr = tok + ((size_t)tb * R + r) * 512;
        float acc = 0.f;
#pragma unroll
        for (int c = 0; c < 8; c++) {
            int d = lane + c * 64;
            acc += tr[d] * sv[d];
        }
#pragma unroll
        for (int off = 32; off; off >>= 1) acc += __shfl_xor(acc, off);
        if (lane == 0) out[(size_t)bid * R + r] = acc;
    }
}

// ---------------- top-16 (values desc, ties -> lowest idx), output sorted asc
__global__ __launch_bounds__(64) void k_topk(const float* __restrict__ simg,
                                             const float* __restrict__ stxt,
                                             int* __restrict__ idx_i, int* __restrict__ idx_t) {
    int bid = blockIdx.x;  // 0..2047: first 1024 img (n=196), then txt (n=77)
    bool isimg = bid < 1024;
    int ij = isimg ? bid : bid - 1024;
    const float* s = isimg ? simg + (size_t)ij * 196 : stxt + (size_t)ij * 77;
    int n = isimg ? 196 : 77;
    int* out = (isimg ? idx_i : idx_t) + ij * 16;
    int lane = threadIdx.x;
    float v[4];
    int ids[4];
#pragma unroll
    for (int k = 0; k < 4; k++) {
        int id = lane + k * 64;
        ids[k] = id;
        v[k] = (id < n) ? s[id] : -3.0e38f;
    }
    __shared__ int sel[16];
    for (int r = 0; r < 16; r++) {
        float bv = v[0];
        int bi = ids[0];
#pragma unroll
        for (int k = 1; k < 4; k++)
            if (v[k] > bv) { bv = v[k]; bi = ids[k]; }
#pragma unroll
        for (int off = 32; off; off >>= 1) {
            float ov = __shfl_xor(bv, off);
            int oi = __shfl_xor(bi, off);
            if (ov > bv || (ov == bv && oi < bi)) { bv = ov; bi = oi; }
        }
        if (lane == 0) sel[r] = bi;
#pragma unroll
        for (int k = 0; k < 4; k++)
            if (ids[k] == bi) v[k] = -3.0e38f;
    }
    if (lane == 0) {
        for (int a = 1; a < 16; a++) {
            int key = sel[a];
            int b = a - 1;
            while (b >= 0 && sel[b] > key) { sel[b + 1] = sel[b]; b--; }
            sel[b + 1] = key;
        }
        for (int a = 0; a < 16; a++) out[a] = sel[a];
    }
}

// ---------------- gather q (f32, into d_out) / k (bf16) token rows ----------
__global__ __launch_bounds__(128) void k_gather(const float* __restrict__ img_n,
                                                const float* __restrict__ txt_n,
                                                const float* __restrict__ img_feat,
                                                const float* __restrict__ txt_feat,
                                                const float* __restrict__ img_cls,
                                                const float* __restrict__ txt_cls,
                                                const int* __restrict__ idx_i,
                                                const int* __restrict__ idx_t,
                                                float* __restrict__ q,
                                                unsigned short* __restrict__ k) {
    int rid = blockIdx.x;  // 0..69631
    int buf = rid / 34816;
    int rem = rid % 34816;
    int seq = rem / 17, t = rem % 17;
    int c = seq >> 10, ij = seq & 1023, i = ij >> 5, j = ij & 31;
    const float* src;
    if (buf == 0) {  // q tensor
        if (c == 0)
            src = (t == 0) ? img_cls : img_n + ((size_t)i * 196 + idx_i[ij * 16 + t - 1]) * 512;
        else
            src = (t == 0) ? txt_cls : txt_n + ((size_t)j * 77 + idx_t[ij * 16 + t - 1]) * 512;
    } else {  // k tensor
        if (c == 0)
            src = (t == 0) ? (txt_feat + (size_t)j * 512)
                           : txt_n + ((size_t)j * 77 + idx_t[ij * 16 + t - 1]) * 512;
        else
            src = (t == 0) ? (img_feat + (size_t)i * 512)
                           : img_n + ((size_t)i * 196 + idx_i[ij * 16 + t - 1]) * 512;
    }
    float4 v = ((const float4*)src)[threadIdx.x];
    size_t row = (size_t)seq * 17 + t;
    if (buf == 0) {
        ((float4*)(q + row * 512))[threadIdx.x] = v;
    } else {
        ushort4 o;
        o.x = f2bf(v.x); o.y = f2bf(v.y); o.z = f2bf(v.z); o.w = f2bf(v.w);
        ((ushort4*)(k + row * 512))[threadIdx.x] = o;
    }
}

// ---------------- LayerNorm 512-wide -> bf16 out; BF: input bf16 else f32 ----
template <int BF>
__global__ __launch_bounds__(256) void k_ln(const void* __restrict__ xv,
                                            const float* __restrict__ w,
                                            const float* __restrict__ b,
                                            unsigned short* __restrict__ out) {
    size_t row = blockIdx.x;
    int t = threadIdx.x;
    float a0, a1;
    if (BF) {
        const short* xr = (const short*)xv + row * 512;
        a0 = bf2f(xr[t]);
        a1 = bf2f(xr[t + 256]);
    } else {
        const float* xr = (const float*)xv + row * 512;
        a0 = xr[t];
        a1 = xr[t + 256];
    }
    float s = a0 + a1, qq = a0 * a0 + a1 * a1;
#pragma unroll
    for (int off = 32; off; off >>= 1) {
        s += __shfl_xor(s, off);
        qq += __shfl_xor(qq, off);
    }
    __shared__ float s4[4], q4[4];
    if ((t & 63) == 0) { s4[t >> 6] = s; q4[t >> 6] = qq; }
    __syncthreads();
    s = s4[0] + s4[1] + s4[2] + s4[3];
    qq = q4[0] + q4[1] + q4[2] + q4[3];
    float mean = s * (1.f / 512.f);
    float var = qq * (1.f / 512.f) - mean * mean;
    float rs = rsqrtf(var + 1e-5f);
    out[row * 512 + t] = f2bf((a0 - mean) * rs * w[t] + b[t]);
    out[row * 512 + t + 256] = f2bf((a1 - mean) * rs * w[t + 256] + b[t + 256]);
}

// ---------------- LDS-staged bf16 MFMA GEMM (m97 structure) -------------------
// C(MxN) = A(MxK) @ W(NxK)^T + bias.   1-D grid, nwg = (M/128)*nxt, nxt = N/128.
// Bijective XCD swizzle; N-tile index varies fastest within an XCD's span so
// the A-panel streams once per XCD while the weight tile stays L2-resident.
// MODE 0: C bf16;  MODE 1: C bf16 = gelu(val);  MODE 2: C f32 += val (residual)
template <int MODE>
__global__ __launch_bounds__(256) void k_gemm(const unsigned short* __restrict__ A,
                                              const unsigned short* __restrict__ W,
                                              const float* __restrict__ bias,
                                              void* __restrict__ Cv, int K, int ldc, int nxt) {
    __shared__ __align__(16) short sA[128 * 64];
    __shared__ __align__(16) short sB[128 * 64];
    // bijective XCD swizzle (m204 variant; works for any nwg)
    int nwg = gridDim.x;
    int orig = blockIdx.x;
    int q8 = nwg >> 3, r8 = nwg & 7;
    int xcd = orig & 7, base = orig >> 3;
    int swz = (xcd < r8 ? xcd * (q8 + 1) : r8 * (q8 + 1) + (xcd - r8) * q8) + base;
    int tn = swz % nxt, tm = swz / nxt;

    int tid = threadIdx.x;
    int lane = tid & 63;
    int w = tid >> 6;
    int wm = w >> 1, wn = w & 1;
    int r16 = lane & 15, g = lane >> 4;

    // staging: wave w covers tile rows [w*32, w*32+32) in 4 loads of 8 rows;
    // lane l -> row offset l>>3, col chunk (l&7)*8 elems (16 B)
    const short* gA = (const short*)A + ((size_t)tm * 128 + w * 32 + (lane >> 3)) * K + (lane & 7) * 8;
    const short* gB = (const short*)W + ((size_t)tn * 128 + w * 32 + (lane >> 3)) * K + (lane & 7) * 8;

    int arow = wm * 64 + r16;
    int brow = wn * 64 + r16;
    f32x4 acc[4][4] = {};

    for (int kk = 0; kk < K; kk += 64) {
#pragma unroll
        for (int i = 0; i < 4; i++) {
            gload16(gA + (size_t)i * 8 * K + kk, &sA[(w * 32 + i * 8) * 64]);
            gload16(gB + (size_t)i * 8 * K + kk, &sB[(w * 32 + i * 8) * 64]);
        }
        __syncthreads();  // drains vmcnt -> LDS tile ready
#pragma unroll
        for (int ks = 0; ks < 2; ks++) {
            short8 a[4], bf[4];
#pragma unroll
            for (int m = 0; m < 4; m++)
                a[m] = *(const short8*)&sA[(arow + m * 16) * 64 + ks * 32 + g * 8];
#pragma unroll
            for (int n = 0; n < 4; n++)
                bf[n] = *(const short8*)&sB[(brow + n * 16) * 64 + ks * 32 + g * 8];
#pragma unroll
            for (int m = 0; m < 4; m++)
#pragma unroll
                for (int n = 0; n < 4; n++)
                    acc[m][n] = __builtin_amdgcn_mfma_f32_16x16x32_bf16(a[m], bf[n], acc[m][n], 0, 0, 0);
        }
        __syncthreads();  // protect LDS before next stage
    }

    size_t rbase = (size_t)tm * 128 + wm * 64 + g * 4;
    size_t cbase = (size_t)tn * 128 + wn * 64 + r16;
#pragma unroll
    for (int m = 0; m < 4; m++)
#pragma unroll
        for (int n = 0; n < 4; n++) {
            size_t col = cbase + n * 16;
            float bv = bias ? bias[col] : 0.f;
#pragma unroll
            for (int r = 0; r < 4; r++) {
                size_t row = rbase + m * 16 + r;
                float val = acc[m][n][r] + bv;
                if (MODE == 0) {
                    ((unsigned short*)Cv)[row * ldc + col] = f2bf(val);
                } else if (MODE == 1) {
                    float gv = val / (1.f + __expf(-1.702f * val));
                    ((unsigned short*)Cv)[row * ldc + col] = f2bf(gv);
                } else {
                    ((float*)Cv)[row * ldc + col] += val;
                }
            }
        }
}

// ---------------- attention: per-seq block (512 thr = 8 waves = 8 heads) ------
__global__ __launch_bounds__(512) void k_attn(const unsigned short* __restrict__ Qm,
                                              const unsigned short* __restrict__ KVm,
                                              unsigned short* __restrict__ Om) {
    __shared__ __align__(16) short sAll[3 * 17 * 520];
    __shared__ float sP[8 * 17 * 17];
    int seq = blockIdx.x;
    size_t tb = (size_t)seq * 17;
    for (int c = threadIdx.x; c < 3264; c += 512) {
        int mat = c / 1088, rem = c % 1088, row = rem >> 6, ch = rem & 63;
        const short8* src;
        if (mat == 0)
            src = (const short8*)(Qm + (tb + row) * 512 + ch * 8);
        else if (mat == 1)
            src = (const short8*)(KVm + (tb + row) * 1024 + ch * 8);
        else
            src = (const short8*)(KVm + (tb + row) * 1024 + 512 + ch * 8);
        *(short8*)&sAll[mat * (17 * 520) + row * 520 + ch * 8] = *src;
    }
    __syncthreads();
    int h = threadIdx.x >> 6, lane = threadIdx.x & 63;
    const short* sQ = sAll;
    const short* sK = sAll + 17 * 520;
    const short* sV = sAll + 2 * 17 * 520;
    int jj = lane < 17 ? lane : 0;
    for (int i = 0; i < 17; i++) {
        float acc = 0.f;
#pragma unroll
        for (int c = 0; c < 8; c++) {
            short8 q8 = *(const short8*)&sQ[i * 520 + h * 64 + c * 8];
            short8 k8 = *(const short8*)&sK[jj * 520 + h * 64 + c * 8];
#pragma unroll
            for (int e = 0; e < 8; e++) acc += bf2f(q8[e]) * bf2f(k8[e]);
        }
        float sc = (lane < 17) ? acc * 0.125f : -1e30f;
        float m = sc;
#pragma unroll
        for (int off = 32; off; off >>= 1) m = fmaxf(m, __shfl_xor(m, off));
        float p = (lane < 17) ? __expf(sc - m) : 0.f;
        float sum = p;
#pragma unroll
        for (int off = 32; off; off >>= 1) sum += __shfl_xor(sum, off);
        if (lane < 17) sP[(h * 17 + i) * 17 + lane] = p / sum;
    }
    for (int i = 0; i < 17; i++) {
        float o = 0.f;
#pragma unroll
        for (int t = 0; t < 17; t++)
            o += sP[(h * 17 + i) * 17 + t] * bf2f(sV[t * 520 + h * 64 + lane]);
        Om[(tb + i) * 512 + h * 64 + lane] = f2bf(o);
    }
}

// ---------------------------------------------------------------------------
extern "C" void kernel_launch(void* const* d_in, const int* in_sizes, int n_in,
                              void* d_out, int out_size, void* d_ws, size_t ws_size,
                              hipStream_t stream) {
    const float* image_feature = (const float*)d_in[0];
    const float* image_tokens = (const float*)d_in[1];
    const float* text_feature = (const float*)d_in[2];
    const float* text_tokens = (const float*)d_in[3];
    const int* atte_mask = (const int*)d_in[4];
    const float* img_cls = (const float*)d_in[5];
    const float* txt_cls = (const float*)d_in[6];
    const float* in_proj_w = (const float*)d_in[7];
    const float* in_proj_b = (const float*)d_in[8];
    const float* out_w = (const float*)d_in[9];
    const float* out_b = (const float*)d_in[10];
    const float* ln1_w = (const float*)d_in[11];
    const float* ln1_b = (const float*)d_in[12];
    const float* ln2_w = (const float*)d_in[13];
    const float* ln2_b = (const float*)d_in[14];
    const float* ln3_w = (const float*)d_in[15];
    const float* ln3_b = (const float*)d_in[16];
    const float* fc_w = (const float*)d_in[17];
    const float* fc_b = (const float*)d_in[18];
    const float* proj_w = (const float*)d_in[19];
    const float* proj_b = (const float*)d_in[20];

    // ---- workspace layout (adaptive; see round-2 notes) ----
    char* ws = (char*)d_ws;
    const size_t OFF_K = 12582912;
    const size_t OFF_CH = OFF_K + 35651584;  // 48,234,496
    size_t avail = ws_size > OFF_CH ? ws_size - OFF_CH : 0;
    int C = 2048;  // seqs per chunk
    while (C > 128 && (size_t)87040 * C > avail) C >>= 1;
    int nch = 2048 / C;

    unsigned short* wbf = (unsigned short*)ws;
    unsigned short* w_inproj = wbf;                // 2*1536*512 elems
    unsigned short* w_outp = wbf + 1572864;        // 2*512*512
    unsigned short* w_fc = wbf + 2097152;          // 2*2048*512
    unsigned short* w_proj = wbf + 4194304;        // 2*512*2048
    unsigned short* kstream = (unsigned short*)(ws + OFF_K);
    char* chreg = ws + OFF_CH;
    // early overlay
    float* img_n = (float*)(chreg + 0);            // 12,845,056
    float* txt_n = (float*)(chreg + 12845056);     //  5,046,272
    float* isum = (float*)(chreg + 17891328);      //     65,536
    float* tmask = (float*)(chreg + 17956864);     //     65,536
    float* simg = (float*)(chreg + 18022400);      //    802,816
    float* stxt = (float*)(chreg + 18825216);      //    315,392
    int* idx_i = (int*)(chreg + 19140608);         //     65,536
    int* idx_t = (int*)(chreg + 19206144);         //     65,536
    // chunk-time pointers
    unsigned short* qn = (unsigned short*)chreg;                      // 17408*C B
    unsigned short* qkvQ = (unsigned short*)(chreg + (size_t)17408 * C);
    unsigned short* qkvKV = (unsigned short*)(chreg + (size_t)34816 * C);
    unsigned short* atto = (unsigned short*)(chreg + (size_t)69632 * C);
    unsigned short* hbuf = qkvQ;  // 69632*C B, overlays qkvQ+qkvKV+atto
    float* q = (float*)d_out;

    // weights -> bf16
    k_f2b<<<1024, 256, 0, stream>>>(in_proj_w, w_inproj, 1572864);
    k_f2b<<<1024, 256, 0, stream>>>(out_w, w_outp, 524288);
    k_f2b<<<1024, 256, 0, stream>>>(fc_w, w_fc, 2097152);
    k_f2b<<<1024, 256, 0, stream>>>(proj_w, w_proj, 2097152);

    // token normalize
    k_l2norm<<<6272, 256, 0, stream>>>(image_tokens, img_n);
    k_l2norm<<<2464, 256, 0, stream>>>(text_tokens, txt_n);

    // factored score vectors
    k_colsum<<<32, 512, 0, stream>>>(img_n, nullptr, isum, 196);
    k_colsum<<<32, 512, 0, stream>>>(txt_n, atte_mask, tmask, 77);

    // scores + top-k + gather (q -> d_out f32, k -> bf16)
    k_scores<<<1024, 256, 0, stream>>>(img_n, tmask, simg, 196, 0);
    k_scores<<<1024, 256, 0, stream>>>(txt_n, isum, stxt, 77, 1);
    k_topk<<<2048, 64, 0, stream>>>(simg, stxt, idx_i, idx_t);
    k_gather<<<69632, 128, 0, stream>>>(img_n, txt_n, image_feature, text_feature,
                                        img_cls, txt_cls, idx_i, idx_t, q, kstream);

    // 2-layer cross-attention transformer, chunked over sequences
    for (int ch = 0; ch < nch; ch++) {
        size_t r0 = (size_t)ch * C * 17;
        float* qc = q + r0 * 512;
        const unsigned short* kc = kstream + r0 * 512;
        int rowsC = 17 * C;
        int gmt = rowsC / 128;  // M-tiles (17*C % 128 == 0 for C in {128..2048})
        for (int l = 0; l < 2; l++) {
            const unsigned short* Wq = w_inproj + (size_t)l * 786432;
            const unsigned short* Wkv = Wq + 262144;
            const float* bq = in_proj_b + l * 1536;
            const float* bkv = bq + 512;
            k_ln<0><<<rowsC, 256, 0, stream>>>(qc, ln1_w + l * 512, ln1_b + l * 512, qn);
            k_gemm<0><<<gmt * 4, 256, 0, stream>>>(qn, Wq, bq, qkvQ, 512, 512, 4);
            k_ln<1><<<rowsC, 256, 0, stream>>>(kc, ln2_w + l * 512, ln2_b + l * 512, qn);
            k_gemm<0><<<gmt * 8, 256, 0, stream>>>(qn, Wkv, bkv, qkvKV, 512, 1024, 8);
            k_attn<<<C, 512, 0, stream>>>(qkvQ, qkvKV, atto);
            k_gemm<2><<<gmt * 4, 256, 0, stream>>>(atto, w_outp + (size_t)l * 262144,
                                                   out_b + l * 512, qc, 512, 512, 4);
            k_ln<0><<<rowsC, 256, 0, stream>>>(qc, ln3_w + l * 512, ln3_b + l * 512, qn);
            k_gemm<1><<<gmt * 16, 256, 0, stream>>>(qn, w_fc + (size_t)l * 1048576,
                                                    fc_b + l * 2048, hbuf, 512, 2048, 16);
            k_gemm<2><<<gmt * 4, 256, 0, stream>>>(hbuf, w_proj + (size_t)l * 1048576,
                                                   proj_b + l * 512, qc, 2048, 512, 4);
        }
    }
}

// Round 4
// 1511.996 us; speedup vs baseline: 1.5721x; 1.1143x over previous
//
#include <hip/hip_runtime.h>
#include <hip/hip_bf16.h>
#include <stdint.h>

// ---------------------------------------------------------------------------
// Alignment_49735721287759: CLIP-style alignment head on MI355X (gfx950)
// Round 4 GEMM: 128x128 tile, BK=64, double-buffered LDS, counted vmcnt(8)
// pipeline (raw s_barrier, never drain-to-0 in loop), T2 XOR-swizzled LDS
// (pre-swizzled global source + swizzled read), bijective XCD swizzle.
// ---------------------------------------------------------------------------

typedef __attribute__((ext_vector_type(8))) short short8;
typedef __attribute__((ext_vector_type(4))) float f32x4;

__device__ __forceinline__ float bf2f(short u) {
    return __uint_as_float(((uint32_t)(uint16_t)u) << 16);
}
__device__ __forceinline__ unsigned short f2bf(float f) {
    __hip_bfloat16 h = __float2bfloat16(f);
    return *reinterpret_cast<unsigned short*>(&h);
}
__device__ __forceinline__ void gload16(const void* g, void* l) {
    __builtin_amdgcn_global_load_lds(
        (const __attribute__((address_space(1))) unsigned int*)g,
        (__attribute__((address_space(3))) unsigned int*)l, 16, 0, 0);
}

// ---------------- f32 -> bf16 convert (weights) ----------------
__global__ __launch_bounds__(256) void k_f2b(const float* __restrict__ in,
                                             unsigned short* __restrict__ out, int n) {
    for (int i = blockIdx.x * 256 + threadIdx.x; i < n; i += gridDim.x * 256)
        out[i] = f2bf(in[i]);
}

// ---------------- row L2 normalize (512-wide rows) ----------------
__global__ __launch_bounds__(256) void k_l2norm(const float* __restrict__ in,
                                                float* __restrict__ out) {
    size_t row = blockIdx.x;
    const float* x = in + row * 512;
    int t = threadIdx.x;
    float a0 = x[t], a1 = x[t + 256];
    float ss = a0 * a0 + a1 * a1;
#pragma unroll
    for (int off = 32; off; off >>= 1) ss += __shfl_xor(ss, off);
    __shared__ float s4[4];
    if ((t & 63) == 0) s4[t >> 6] = ss;
    __syncthreads();
    float tot = s4[0] + s4[1] + s4[2] + s4[3];
    float inv = 1.0f / sqrtf(tot);
    out[row * 512 + t] = a0 * inv;
    out[row * 512 + t + 256] = a1 * inv;
}

// ---------------- column sum over tokens (optionally masked) ----------------
__global__ __launch_bounds__(512) void k_colsum(const float* __restrict__ tok,
                                                const int* __restrict__ mask,
                                                float* __restrict__ out, int R) {
    int b = blockIdx.x;
    int d = threadIdx.x;  // 512 threads
    float acc = 0.f;
    for (int r = 0; r < R; r++) {
        float m = mask ? (float)mask[b * R + r] : 1.f;
        acc += m * tok[((size_t)b * R + r) * 512 + d];
    }
    out[b * 512 + d] = acc;
}

// ---------------- factored scores ----------------
__global__ __launch_bounds__(256) void k_scores(const float* __restrict__ tok,
                                                const float* __restrict__ vec,
                                                float* __restrict__ out, int R, int swap) {
    int bid = blockIdx.x;
    int i = bid >> 5, j = bid & 31;
    int tb = swap ? j : i;
    int vb = swap ? i : j;
    __shared__ float sv[512];
    for (int t = threadIdx.x; t < 512; t += 256) sv[t] = vec[vb * 512 + t];
    __syncthreads();
    int wv = threadIdx.x >> 6, lane = threadIdx.x & 63;
    for (int r = wv; r < R; r += 4) {
        const float* tr = tok + ((size_t)tb * R + r) * 512;
        float acc = 0.f;
#pragma unroll
        for (int c = 0; c < 8; c++) {
            int d = lane + c * 64;
            acc += tr[d] * sv[d];
        }
#pragma unroll
        for (int off = 32; off; off >>= 1) acc += __shfl_xor(acc, off);
        if (lane == 0) out[(size_t)bid * R + r] = acc;
    }
}

// ---------------- top-16 (values desc, ties -> lowest idx), output sorted asc
__global__ __launch_bounds__(64) void k_topk(const float* __restrict__ simg,
                                             const float* __restrict__ stxt,
                                             int* __restrict__ idx_i, int* __restrict__ idx_t) {
    int bid = blockIdx.x;  // 0..2047: first 1024 img (n=196), then txt (n=77)
    bool isimg = bid < 1024;
    int ij = isimg ? bid : bid - 1024;
    const float* s = isimg ? simg + (size_t)ij * 196 : stxt + (size_t)ij * 77;
    int n = isimg ? 196 : 77;
    int* out = (isimg ? idx_i : idx_t) + ij * 16;
    int lane = threadIdx.x;
    float v[4];
    int ids[4];
#pragma unroll
    for (int k = 0; k < 4; k++) {
        int id = lane + k * 64;
        ids[k] = id;
        v[k] = (id < n) ? s[id] : -3.0e38f;
    }
    __shared__ int sel[16];
    for (int r = 0; r < 16; r++) {
        float bv = v[0];
        int bi = ids[0];
#pragma unroll
        for (int k = 1; k < 4; k++)
            if (v[k] > bv) { bv = v[k]; bi = ids[k]; }
#pragma unroll
        for (int off = 32; off; off >>= 1) {
            float ov = __shfl_xor(bv, off);
            int oi = __shfl_xor(bi, off);
            if (ov > bv || (ov == bv && oi < bi)) { bv = ov; bi = oi; }
        }
        if (lane == 0) sel[r] = bi;
#pragma unroll
        for (int k = 0; k < 4; k++)
            if (ids[k] == bi) v[k] = -3.0e38f;
    }
    if (lane == 0) {
        for (int a = 1; a < 16; a++) {
            int key = sel[a];
            int b = a - 1;
            while (b >= 0 && sel[b] > key) { sel[b + 1] = sel[b]; b--; }
            sel[b + 1] = key;
        }
        for (int a = 0; a < 16; a++) out[a] = sel[a];
    }
}

// ---------------- gather q (f32, into d_out) / k (bf16) token rows ----------
__global__ __launch_bounds__(128) void k_gather(const float* __restrict__ img_n,
                                                const float* __restrict__ txt_n,
                                                const float* __restrict__ img_feat,
                                                const float* __restrict__ txt_feat,
                                                const float* __restrict__ img_cls,
                                                const float* __restrict__ txt_cls,
                                                const int* __restrict__ idx_i,
                                                const int* __restrict__ idx_t,
                                                float* __restrict__ q,
                                                unsigned short* __restrict__ k) {
    int rid = blockIdx.x;  // 0..69631
    int buf = rid / 34816;
    int rem = rid % 34816;
    int seq = rem / 17, t = rem % 17;
    int c = seq >> 10, ij = seq & 1023, i = ij >> 5, j = ij & 31;
    const float* src;
    if (buf == 0) {  // q tensor
        if (c == 0)
            src = (t == 0) ? img_cls : img_n + ((size_t)i * 196 + idx_i[ij * 16 + t - 1]) * 512;
        else
            src = (t == 0) ? txt_cls : txt_n + ((size_t)j * 77 + idx_t[ij * 16 + t - 1]) * 512;
    } else {  // k tensor
        if (c == 0)
            src = (t == 0) ? (txt_feat + (size_t)j * 512)
                           : txt_n + ((size_t)j * 77 + idx_t[ij * 16 + t - 1]) * 512;
        else
            src = (t == 0) ? (img_feat + (size_t)i * 512)
                           : img_n + ((size_t)i * 196 + idx_i[ij * 16 + t - 1]) * 512;
    }
    float4 v = ((const float4*)src)[threadIdx.x];
    size_t row = (size_t)seq * 17 + t;
    if (buf == 0) {
        ((float4*)(q + row * 512))[threadIdx.x] = v;
    } else {
        ushort4 o;
        o.x = f2bf(v.x); o.y = f2bf(v.y); o.z = f2bf(v.z); o.w = f2bf(v.w);
        ((ushort4*)(k + row * 512))[threadIdx.x] = o;
    }
}

// ---------------- LayerNorm 512-wide -> bf16 out; BF: input bf16 else f32 ----
template <int BF>
__global__ __launch_bounds__(256) void k_ln(const void* __restrict__ xv,
                                            const float* __restrict__ w,
                                            const float* __restrict__ b,
                                            unsigned short* __restrict__ out) {
    size_t row = blockIdx.x;
    int t = threadIdx.x;
    float a0, a1;
    if (BF) {
        const short* xr = (const short*)xv + row * 512;
        a0 = bf2f(xr[t]);
        a1 = bf2f(xr[t + 256]);
    } else {
        const float* xr = (const float*)xv + row * 512;
        a0 = xr[t];
        a1 = xr[t + 256];
    }
    float s = a0 + a1, qq = a0 * a0 + a1 * a1;
#pragma unroll
    for (int off = 32; off; off >>= 1) {
        s += __shfl_xor(s, off);
        qq += __shfl_xor(qq, off);
    }
    __shared__ float s4[4], q4[4];
    if ((t & 63) == 0) { s4[t >> 6] = s; q4[t >> 6] = qq; }
    __syncthreads();
    s = s4[0] + s4[1] + s4[2] + s4[3];
    qq = q4[0] + q4[1] + q4[2] + q4[3];
    float mean = s * (1.f / 512.f);
    float var = qq * (1.f / 512.f) - mean * mean;
    float rs = rsqrtf(var + 1e-5f);
    out[row * 512 + t] = f2bf((a0 - mean) * rs * w[t] + b[t]);
    out[row * 512 + t + 256] = f2bf((a1 - mean) * rs * w[t + 256] + b[t + 256]);
}

// ---------------- pipelined LDS-dbuf bf16 MFMA GEMM --------------------------
// C(MxN) = A(MxK) @ W(NxK)^T + bias.  1-D grid, nwg = (M/128)*nxt, nxt = N/128.
// Counted-vmcnt double-buffer: tile t+2 staged after computing tile t; main
// loop waits vmcnt(8) (next tile's 8 loads stay in flight across barrier).
// T2 XOR swizzle: global source chunk pre-swizzled, LDS dest linear, read
// slot XOR'd -> 2-way (free) instead of 16-way bank conflict.
// MODE 0: C bf16;  MODE 1: C bf16 = gelu(val);  MODE 2: C f32 += val.
template <int MODE>
__global__ __launch_bounds__(256) void k_gemm(const unsigned short* __restrict__ A,
                                              const unsigned short* __restrict__ W,
                                              const float* __restrict__ bias,
                                              void* __restrict__ Cv, int K, int ldc, int nxt) {
    __shared__ __align__(16) short sA[2][128 * 64];
    __shared__ __align__(16) short sB[2][128 * 64];
    // bijective XCD swizzle (m204 variant)
    int nwg = gridDim.x;
    int orig = blockIdx.x;
    int q8 = nwg >> 3, r8 = nwg & 7;
    int xcd = orig & 7, base = orig >> 3;
    int swz = (xcd < r8 ? xcd * (q8 + 1) : r8 * (q8 + 1) + (xcd - r8) * q8) + base;
    int tn = swz % nxt, tm = swz / nxt;

    int tid = threadIdx.x;
    int lane = tid & 63;
    int w = tid >> 6;
    int wm = w >> 1, wn = w & 1;
    int r16 = lane & 15, g = lane >> 4;

    // staging: wave w covers tile rows [w*32, w*32+32) in 4 gload16 of 8 rows.
    // lane l -> row l>>3, 16B-chunk (l&7) XOR row (pre-swizzled source).
    int srow = lane >> 3;
    int schunk = (lane & 7) ^ srow;
    const short* gA = (const short*)A + ((size_t)tm * 128 + w * 32 + srow) * K + schunk * 8;
    const short* gB = (const short*)W + ((size_t)tn * 128 + w * 32 + srow) * K + schunk * 8;

    int arow = wm * 64 + r16;
    int brow = wn * 64 + r16;
    f32x4 acc[4][4] = {};
    int nt = K >> 6;

    // prologue: stage tiles 0 and 1
#pragma unroll
    for (int i = 0; i < 4; i++) {
        gload16(gA + (size_t)i * 8 * K, &sA[0][(w * 32 + i * 8) * 64]);
        gload16(gB + (size_t)i * 8 * K, &sB[0][(w * 32 + i * 8) * 64]);
    }
    if (nt > 1) {
#pragma unroll
        for (int i = 0; i < 4; i++) {
            gload16(gA + (size_t)i * 8 * K + 64, &sA[1][(w * 32 + i * 8) * 64]);
            gload16(gB + (size_t)i * 8 * K + 64, &sB[1][(w * 32 + i * 8) * 64]);
        }
    }

    int cur = 0;
    for (int t = 0; t < nt; t++) {
        // own tile's loads done; next tile's (<=8) stay in flight
        if (t + 1 < nt) asm volatile("s_waitcnt vmcnt(8)" ::: "memory");
        else            asm volatile("s_waitcnt vmcnt(0)" ::: "memory");
        __builtin_amdgcn_s_barrier();
        __builtin_amdgcn_sched_barrier(0);
#pragma unroll
        for (int ks = 0; ks < 2; ks++) {
            short8 a[4], bq[4];
#pragma unroll
            for (int m = 0; m < 4; m++) {
                int row = arow + m * 16;
                int slot = (ks * 4 + g) ^ (row & 7);
                a[m] = *(const short8*)&sA[cur][row * 64 + slot * 8];
            }
#pragma unroll
            for (int n = 0; n < 4; n++) {
                int row = brow + n * 16;
                int slot = (ks * 4 + g) ^ (row & 7);
                bq[n] = *(const short8*)&sB[cur][row * 64 + slot * 8];
            }
#pragma unroll
            for (int m = 0; m < 4; m++)
#pragma unroll
                for (int n = 0; n < 4; n++)
                    acc[m][n] = __builtin_amdgcn_mfma_f32_16x16x32_bf16(a[m], bq[n], acc[m][n], 0, 0, 0);
        }
        if (t + 2 < nt) {
            __builtin_amdgcn_s_barrier();  // all waves done reading buf[cur]
            size_t koff = (size_t)(t + 2) * 64;
#pragma unroll
            for (int i = 0; i < 4; i++) {
                gload16(gA + (size_t)i * 8 * K + koff, &sA[cur][(w * 32 + i * 8) * 64]);
                gload16(gB + (size_t)i * 8 * K + koff, &sB[cur][(w * 32 + i * 8) * 64]);
            }
        }
        cur ^= 1;
    }

    size_t rbase = (size_t)tm * 128 + wm * 64 + g * 4;
    size_t cbase = (size_t)tn * 128 + wn * 64 + r16;
#pragma unroll
    for (int m = 0; m < 4; m++)
#pragma unroll
        for (int n = 0; n < 4; n++) {
            size_t col = cbase + n * 16;
            float bv = bias ? bias[col] : 0.f;
#pragma unroll
            for (int r = 0; r < 4; r++) {
                size_t row = rbase + m * 16 + r;
                float val = acc[m][n][r] + bv;
                if (MODE == 0) {
                    ((unsigned short*)Cv)[row * ldc + col] = f2bf(val);
                } else if (MODE == 1) {
                    float gv = val / (1.f + __expf(-1.702f * val));
                    ((unsigned short*)Cv)[row * ldc + col] = f2bf(gv);
                } else {
                    ((float*)Cv)[row * ldc + col] += val;
                }
            }
        }
}

// ---------------- attention: per-seq block (512 thr = 8 waves = 8 heads) ------
__global__ __launch_bounds__(512) void k_attn(const unsigned short* __restrict__ Qm,
                                              const unsigned short* __restrict__ KVm,
                                              unsigned short* __restrict__ Om) {
    __shared__ __align__(16) short sAll[3 * 17 * 520];
    __shared__ float sP[8 * 17 * 17];
    int seq = blockIdx.x;
    size_t tb = (size_t)seq * 17;
    for (int c = threadIdx.x; c < 3264; c += 512) {
        int mat = c / 1088, rem = c % 1088, row = rem >> 6, ch = rem & 63;
        const short8* src;
        if (mat == 0)
            src = (const short8*)(Qm + (tb + row) * 512 + ch * 8);
        else if (mat == 1)
            src = (const short8*)(KVm + (tb + row) * 1024 + ch * 8);
        else
            src = (const short8*)(KVm + (tb + row) * 1024 + 512 + ch * 8);
        *(short8*)&sAll[mat * (17 * 520) + row * 520 + ch * 8] = *src;
    }
    __syncthreads();
    int h = threadIdx.x >> 6, lane = threadIdx.x & 63;
    const short* sQ = sAll;
    const short* sK = sAll + 17 * 520;
    const short* sV = sAll + 2 * 17 * 520;
    int jj = lane < 17 ? lane : 0;
    for (int i = 0; i < 17; i++) {
        float acc = 0.f;
#pragma unroll
        for (int c = 0; c < 8; c++) {
            short8 q8 = *(const short8*)&sQ[i * 520 + h * 64 + c * 8];
            short8 k8 = *(const short8*)&sK[jj * 520 + h * 64 + c * 8];
#pragma unroll
            for (int e = 0; e < 8; e++) acc += bf2f(q8[e]) * bf2f(k8[e]);
        }
        float sc = (lane < 17) ? acc * 0.125f : -1e30f;
        float m = sc;
#pragma unroll
        for (int off = 32; off; off >>= 1) m = fmaxf(m, __shfl_xor(m, off));
        float p = (lane < 17) ? __expf(sc - m) : 0.f;
        float sum = p;
#pragma unroll
        for (int off = 32; off; off >>= 1) sum += __shfl_xor(sum, off);
        if (lane < 17) sP[(h * 17 + i) * 17 + lane] = p / sum;
    }
    for (int i = 0; i < 17; i++) {
        float o = 0.f;
#pragma unroll
        for (int t = 0; t < 17; t++)
            o += sP[(h * 17 + i) * 17 + t] * bf2f(sV[t * 520 + h * 64 + lane]);
        Om[(tb + i) * 512 + h * 64 + lane] = f2bf(o);
    }
}

// ---------------------------------------------------------------------------
extern "C" void kernel_launch(void* const* d_in, const int* in_sizes, int n_in,
                              void* d_out, int out_size, void* d_ws, size_t ws_size,
                              hipStream_t stream) {
    const float* image_feature = (const float*)d_in[0];
    const float* image_tokens = (const float*)d_in[1];
    const float* text_feature = (const float*)d_in[2];
    const float* text_tokens = (const float*)d_in[3];
    const int* atte_mask = (const int*)d_in[4];
    const float* img_cls = (const float*)d_in[5];
    const float* txt_cls = (const float*)d_in[6];
    const float* in_proj_w = (const float*)d_in[7];
    const float* in_proj_b = (const float*)d_in[8];
    const float* out_w = (const float*)d_in[9];
    const float* out_b = (const float*)d_in[10];
    const float* ln1_w = (const float*)d_in[11];
    const float* ln1_b = (const float*)d_in[12];
    const float* ln2_w = (const float*)d_in[13];
    const float* ln2_b = (const float*)d_in[14];
    const float* ln3_w = (const float*)d_in[15];
    const float* ln3_b = (const float*)d_in[16];
    const float* fc_w = (const float*)d_in[17];
    const float* fc_b = (const float*)d_in[18];
    const float* proj_w = (const float*)d_in[19];
    const float* proj_b = (const float*)d_in[20];

    // ---- workspace layout (adaptive; see round-2 notes) ----
    char* ws = (char*)d_ws;
    const size_t OFF_K = 12582912;
    const size_t OFF_CH = OFF_K + 35651584;  // 48,234,496
    size_t avail = ws_size > OFF_CH ? ws_size - OFF_CH : 0;
    int C = 2048;  // seqs per chunk
    while (C > 128 && (size_t)87040 * C > avail) C >>= 1;
    int nch = 2048 / C;

    unsigned short* wbf = (unsigned short*)ws;
    unsigned short* w_inproj = wbf;                // 2*1536*512 elems
    unsigned short* w_outp = wbf + 1572864;        // 2*512*512
    unsigned short* w_fc = wbf + 2097152;          // 2*2048*512
    unsigned short* w_proj = wbf + 4194304;        // 2*512*2048
    unsigned short* kstream = (unsigned short*)(ws + OFF_K);
    char* chreg = ws + OFF_CH;
    // early overlay
    float* img_n = (float*)(chreg + 0);            // 12,845,056
    float* txt_n = (float*)(chreg + 12845056);     //  5,046,272
    float* isum = (float*)(chreg + 17891328);      //     65,536
    float* tmask = (float*)(chreg + 17956864);     //     65,536
    float* simg = (float*)(chreg + 18022400);      //    802,816
    float* stxt = (float*)(chreg + 18825216);      //    315,392
    int* idx_i = (int*)(chreg + 19140608);         //     65,536
    int* idx_t = (int*)(chreg + 19206144);         //     65,536
    // chunk-time pointers
    unsigned short* qn = (unsigned short*)chreg;                      // 17408*C B
    unsigned short* qkvQ = (unsigned short*)(chreg + (size_t)17408 * C);
    unsigned short* qkvKV = (unsigned short*)(chreg + (size_t)34816 * C);
    unsigned short* atto = (unsigned short*)(chreg + (size_t)69632 * C);
    unsigned short* hbuf = qkvQ;  // 69632*C B, overlays qkvQ+qkvKV+atto
    float* q = (float*)d_out;

    // weights -> bf16
    k_f2b<<<1024, 256, 0, stream>>>(in_proj_w, w_inproj, 1572864);
    k_f2b<<<1024, 256, 0, stream>>>(out_w, w_outp, 524288);
    k_f2b<<<1024, 256, 0, stream>>>(fc_w, w_fc, 2097152);
    k_f2b<<<1024, 256, 0, stream>>>(proj_w, w_proj, 2097152);

    // token normalize
    k_l2norm<<<6272, 256, 0, stream>>>(image_tokens, img_n);
    k_l2norm<<<2464, 256, 0, stream>>>(text_tokens, txt_n);

    // factored score vectors
    k_colsum<<<32, 512, 0, stream>>>(img_n, nullptr, isum, 196);
    k_colsum<<<32, 512, 0, stream>>>(txt_n, atte_mask, tmask, 77);

    // scores + top-k + gather (q -> d_out f32, k -> bf16)
    k_scores<<<1024, 256, 0, stream>>>(img_n, tmask, simg, 196, 0);
    k_scores<<<1024, 256, 0, stream>>>(txt_n, isum, stxt, 77, 1);
    k_topk<<<2048, 64, 0, stream>>>(simg, stxt, idx_i, idx_t);
    k_gather<<<69632, 128, 0, stream>>>(img_n, txt_n, image_feature, text_feature,
                                        img_cls, txt_cls, idx_i, idx_t, q, kstream);

    // 2-layer cross-attention transformer, chunked over sequences
    for (int ch = 0; ch < nch; ch++) {
        size_t r0 = (size_t)ch * C * 17;
        float* qc = q + r0 * 512;
        const unsigned short* kc = kstream + r0 * 512;
        int rowsC = 17 * C;
        int gmt = rowsC / 128;  // M-tiles
        for (int l = 0; l < 2; l++) {
            const unsigned short* Wq = w_inproj + (size_t)l * 786432;
            const unsigned short* Wkv = Wq + 262144;
            const float* bq = in_proj_b + l * 1536;
            const float* bkv = bq + 512;
            k_ln<0><<<rowsC, 256, 0, stream>>>(qc, ln1_w + l * 512, ln1_b + l * 512, qn);
            k_gemm<0><<<gmt * 4, 256, 0, stream>>>(qn, Wq, bq, qkvQ, 512, 512, 4);
            k_ln<1><<<rowsC, 256, 0, stream>>>(kc, ln2_w + l * 512, ln2_b + l * 512, qn);
            k_gemm<0><<<gmt * 8, 256, 0, stream>>>(qn, Wkv, bkv, qkvKV, 512, 1024, 8);
            k_attn<<<C, 512, 0, stream>>>(qkvQ, qkvKV, atto);
            k_gemm<2><<<gmt * 4, 256, 0, stream>>>(atto, w_outp + (size_t)l * 262144,
                                                   out_b + l * 512, qc, 512, 512, 4);
            k_ln<0><<<rowsC, 256, 0, stream>>>(qc, ln3_w + l * 512, ln3_b + l * 512, qn);
            k_gemm<1><<<gmt * 16, 256, 0, stream>>>(qn, w_fc + (size_t)l * 1048576,
                                                    fc_b + l * 2048, hbuf, 512, 2048, 16);
            k_gemm<2><<<gmt * 4, 256, 0, stream>>>(hbuf, w_proj + (size_t)l * 1048576,
                                                   proj_b + l * 512, qc, 2048, 512, 4);
        }
    }
}

// Round 5
// 1477.081 us; speedup vs baseline: 1.6093x; 1.0236x over previous
//
#include <hip/hip_runtime.h>
#include <hip/hip_bf16.h>
#include <stdint.h>

// ---------------------------------------------------------------------------
// Alignment_49735721287759: CLIP-style alignment head on MI355X (gfx950)
// Round 5 GEMM: 128x128 tile, K-units of 32, 4-slot LDS ring (64KB),
// counted vmcnt(12) depth-3 pipeline (never drain-to-0 mid-loop),
// XOR-swizzled staging/reads (bank-conflict-free), setprio around MFMA,
// bijective XCD swizzle. 2 blocks/CU TLP preserved.
// ---------------------------------------------------------------------------

typedef __attribute__((ext_vector_type(8))) short short8;
typedef __attribute__((ext_vector_type(4))) float f32x4;

__device__ __forceinline__ float bf2f(short u) {
    return __uint_as_float(((uint32_t)(uint16_t)u) << 16);
}
__device__ __forceinline__ unsigned short f2bf(float f) {
    __hip_bfloat16 h = __float2bfloat16(f);
    return *reinterpret_cast<unsigned short*>(&h);
}
__device__ __forceinline__ void gload16(const void* g, void* l) {
    __builtin_amdgcn_global_load_lds(
        (const __attribute__((address_space(1))) unsigned int*)g,
        (__attribute__((address_space(3))) unsigned int*)l, 16, 0, 0);
}

// ---------------- f32 -> bf16 convert (weights) ----------------
__global__ __launch_bounds__(256) void k_f2b(const float* __restrict__ in,
                                             unsigned short* __restrict__ out, int n) {
    for (int i = blockIdx.x * 256 + threadIdx.x; i < n; i += gridDim.x * 256)
        out[i] = f2bf(in[i]);
}

// ---------------- row L2 normalize (512-wide rows) ----------------
__global__ __launch_bounds__(256) void k_l2norm(const float* __restrict__ in,
                                                float* __restrict__ out) {
    size_t row = blockIdx.x;
    const float* x = in + row * 512;
    int t = threadIdx.x;
    float a0 = x[t], a1 = x[t + 256];
    float ss = a0 * a0 + a1 * a1;
#pragma unroll
    for (int off = 32; off; off >>= 1) ss += __shfl_xor(ss, off);
    __shared__ float s4[4];
    if ((t & 63) == 0) s4[t >> 6] = ss;
    __syncthreads();
    float tot = s4[0] + s4[1] + s4[2] + s4[3];
    float inv = 1.0f / sqrtf(tot);
    out[row * 512 + t] = a0 * inv;
    out[row * 512 + t + 256] = a1 * inv;
}

// ---------------- column sum over tokens (optionally masked) ----------------
__global__ __launch_bounds__(512) void k_colsum(const float* __restrict__ tok,
                                                const int* __restrict__ mask,
                                                float* __restrict__ out, int R) {
    int b = blockIdx.x;
    int d = threadIdx.x;  // 512 threads
    float acc = 0.f;
    for (int r = 0; r < R; r++) {
        float m = mask ? (float)mask[b * R + r] : 1.f;
        acc += m * tok[((size_t)b * R + r) * 512 + d];
    }
    out[b * 512 + d] = acc;
}

// ---------------- factored scores ----------------
__global__ __launch_bounds__(256) void k_scores(const float* __restrict__ tok,
                                                const float* __restrict__ vec,
                                                float* __restrict__ out, int R, int swap) {
    int bid = blockIdx.x;
    int i = bid >> 5, j = bid & 31;
    int tb = swap ? j : i;
    int vb = swap ? i : j;
    __shared__ float sv[512];
    for (int t = threadIdx.x; t < 512; t += 256) sv[t] = vec[vb * 512 + t];
    __syncthreads();
    int wv = threadIdx.x >> 6, lane = threadIdx.x & 63;
    for (int r = wv; r < R; r += 4) {
        const float* tr = tok + ((size_t)tb * R + r) * 512;
        float acc = 0.f;
#pragma unroll
        for (int c = 0; c < 8; c++) {
            int d = lane + c * 64;
            acc += tr[d] * sv[d];
        }
#pragma unroll
        for (int off = 32; off; off >>= 1) acc += __shfl_xor(acc, off);
        if (lane == 0) out[(size_t)bid * R + r] = acc;
    }
}

// ---------------- top-16 (values desc, ties -> lowest idx), output sorted asc
__global__ __launch_bounds__(64) void k_topk(const float* __restrict__ simg,
                                             const float* __restrict__ stxt,
                                             int* __restrict__ idx_i, int* __restrict__ idx_t) {
    int bid = blockIdx.x;  // 0..2047: first 1024 img (n=196), then txt (n=77)
    bool isimg = bid < 1024;
    int ij = isimg ? bid : bid - 1024;
    const float* s = isimg ? simg + (size_t)ij * 196 : stxt + (size_t)ij * 77;
    int n = isimg ? 196 : 77;
    int* out = (isimg ? idx_i : idx_t) + ij * 16;
    int lane = threadIdx.x;
    float v[4];
    int ids[4];
#pragma unroll
    for (int k = 0; k < 4; k++) {
        int id = lane + k * 64;
        ids[k] = id;
        v[k] = (id < n) ? s[id] : -3.0e38f;
    }
    __shared__ int sel[16];
    for (int r = 0; r < 16; r++) {
        float bv = v[0];
        int bi = ids[0];
#pragma unroll
        for (int k = 1; k < 4; k++)
            if (v[k] > bv) { bv = v[k]; bi = ids[k]; }
#pragma unroll
        for (int off = 32; off; off >>= 1) {
            float ov = __shfl_xor(bv, off);
            int oi = __shfl_xor(bi, off);
            if (ov > bv || (ov == bv && oi < bi)) { bv = ov; bi = oi; }
        }
        if (lane == 0) sel[r] = bi;
#pragma unroll
        for (int k = 0; k < 4; k++)
            if (ids[k] == bi) v[k] = -3.0e38f;
    }
    if (lane == 0) {
        for (int a = 1; a < 16; a++) {
            int key = sel[a];
            int b = a - 1;
            while (b >= 0 && sel[b] > key) { sel[b + 1] = sel[b]; b--; }
            sel[b + 1] = key;
        }
        for (int a = 0; a < 16; a++) out[a] = sel[a];
    }
}

// ---------------- gather q (f32, into d_out) / k (bf16) token rows ----------
__global__ __launch_bounds__(128) void k_gather(const float* __restrict__ img_n,
                                                const float* __restrict__ txt_n,
                                                const float* __restrict__ img_feat,
                                                const float* __restrict__ txt_feat,
                                                const float* __restrict__ img_cls,
                                                const float* __restrict__ txt_cls,
                                                const int* __restrict__ idx_i,
                                                const int* __restrict__ idx_t,
                                                float* __restrict__ q,
                                                unsigned short* __restrict__ k) {
    int rid = blockIdx.x;  // 0..69631
    int buf = rid / 34816;
    int rem = rid % 34816;
    int seq = rem / 17, t = rem % 17;
    int c = seq >> 10, ij = seq & 1023, i = ij >> 5, j = ij & 31;
    const float* src;
    if (buf == 0) {  // q tensor
        if (c == 0)
            src = (t == 0) ? img_cls : img_n + ((size_t)i * 196 + idx_i[ij * 16 + t - 1]) * 512;
        else
            src = (t == 0) ? txt_cls : txt_n + ((size_t)j * 77 + idx_t[ij * 16 + t - 1]) * 512;
    } else {  // k tensor
        if (c == 0)
            src = (t == 0) ? (txt_feat + (size_t)j * 512)
                           : txt_n + ((size_t)j * 77 + idx_t[ij * 16 + t - 1]) * 512;
        else
            src = (t == 0) ? (img_feat + (size_t)i * 512)
                           : img_n + ((size_t)i * 196 + idx_i[ij * 16 + t - 1]) * 512;
    }
    float4 v = ((const float4*)src)[threadIdx.x];
    size_t row = (size_t)seq * 17 + t;
    if (buf == 0) {
        ((float4*)(q + row * 512))[threadIdx.x] = v;
    } else {
        ushort4 o;
        o.x = f2bf(v.x); o.y = f2bf(v.y); o.z = f2bf(v.z); o.w = f2bf(v.w);
        ((ushort4*)(k + row * 512))[threadIdx.x] = o;
    }
}

// ---------------- LayerNorm 512-wide -> bf16 out; BF: input bf16 else f32 ----
template <int BF>
__global__ __launch_bounds__(256) void k_ln(const void* __restrict__ xv,
                                            const float* __restrict__ w,
                                            const float* __restrict__ b,
                                            unsigned short* __restrict__ out) {
    size_t row = blockIdx.x;
    int t = threadIdx.x;
    float a0, a1;
    if (BF) {
        const short* xr = (const short*)xv + row * 512;
        a0 = bf2f(xr[t]);
        a1 = bf2f(xr[t + 256]);
    } else {
        const float* xr = (const float*)xv + row * 512;
        a0 = xr[t];
        a1 = xr[t + 256];
    }
    float s = a0 + a1, qq = a0 * a0 + a1 * a1;
#pragma unroll
    for (int off = 32; off; off >>= 1) {
        s += __shfl_xor(s, off);
        qq += __shfl_xor(qq, off);
    }
    __shared__ float s4[4], q4[4];
    if ((t & 63) == 0) { s4[t >> 6] = s; q4[t >> 6] = qq; }
    __syncthreads();
    s = s4[0] + s4[1] + s4[2] + s4[3];
    qq = q4[0] + q4[1] + q4[2] + q4[3];
    float mean = s * (1.f / 512.f);
    float var = qq * (1.f / 512.f) - mean * mean;
    float rs = rsqrtf(var + 1e-5f);
    out[row * 512 + t] = f2bf((a0 - mean) * rs * w[t] + b[t]);
    out[row * 512 + t + 256] = f2bf((a1 - mean) * rs * w[t + 256] + b[t + 256]);
}

// ---------------- unit-pipelined bf16 MFMA GEMM ------------------------------
// C(MxN) = A(MxK) @ W(NxK)^T + bias.  1-D grid, nwg = (M/128)*nxt, nxt = N/128.
// K split into units of 32. LDS ring of 4 slots (16KB each: A[128][32]+B[128][32]).
// Per unit: wait vmcnt(12) -> barrier -> 8x ds_read_b128 (XOR swizzle) ->
// setprio(1) 16 MFMA setprio(0) -> barrier -> stage unit u+4 into freed slot.
// Loads stay 3 units (~600cyc) in flight; vmcnt never drains mid-loop.
// MODE 0: C bf16;  MODE 1: C bf16 = gelu(val);  MODE 2: C f32 += val.
template <int MODE>
__global__ __launch_bounds__(256) void k_gemm(const unsigned short* __restrict__ A,
                                              const unsigned short* __restrict__ W,
                                              const float* __restrict__ bias,
                                              void* __restrict__ Cv, int K, int ldc, int nxt) {
    __shared__ __align__(16) short sU[4][8192];  // slot: A 4096 elems | B 4096 elems

    // bijective XCD swizzle (m204 variant)
    int nwg = gridDim.x;
    int orig = blockIdx.x;
    int q8 = nwg >> 3, r8 = nwg & 7;
    int xcd = orig & 7, base = orig >> 3;
    int swz = (xcd < r8 ? xcd * (q8 + 1) : r8 * (q8 + 1) + (xcd - r8) * q8) + base;
    int tn = swz % nxt, tm = swz / nxt;

    int tid = threadIdx.x;
    int lane = tid & 63;
    int w = tid >> 6;
    int wm = w >> 1, wn = w & 1;
    int r16 = lane & 15, g = lane >> 4;

    // staging: srow = tid>>2 in 0..63 (two 64-row groups per operand),
    // 16B chunk (tid&3) XOR'd with row (pre-swizzled global source).
    int srow = tid >> 2;
    int schunk = tid & 3;
    int kchunk = (schunk ^ (srow & 3)) * 8;  // (srow+64)&3 == srow&3
    const short* gA = (const short*)A + ((size_t)tm * 128 + srow) * K + kchunk;
    const short* gB = (const short*)W + ((size_t)tn * 128 + srow) * K + kchunk;
    int ldst = srow * 32 + schunk * 8;  // elem offset; per-wave = base + lane*16B

    f32x4 acc[4][4] = {};
    int NU = K >> 5;  // units of 32 (K is 512 or 2048 -> NU 16 or 64)

#define STAGE_UNIT(U, S)                                              \
    do {                                                              \
        size_t ko_ = (size_t)(U) * 32;                                \
        gload16(gA + ko_, &sU[(S)][ldst]);                            \
        gload16(gA + (size_t)64 * K + ko_, &sU[(S)][2048 + ldst]);    \
        gload16(gB + ko_, &sU[(S)][4096 + ldst]);                     \
        gload16(gB + (size_t)64 * K + ko_, &sU[(S)][6144 + ldst]);    \
    } while (0)

    STAGE_UNIT(0, 0);
    STAGE_UNIT(1, 1);
    STAGE_UNIT(2, 2);
    STAGE_UNIT(3, 3);

    int s = 0;
    for (int u = 0; u < NU; ++u) {
        int rem = NU - 1 - u;
        if (rem >= 3)      asm volatile("s_waitcnt vmcnt(12)" ::: "memory");
        else if (rem == 2) asm volatile("s_waitcnt vmcnt(8)" ::: "memory");
        else if (rem == 1) asm volatile("s_waitcnt vmcnt(4)" ::: "memory");
        else               asm volatile("s_waitcnt vmcnt(0)" ::: "memory");
        __builtin_amdgcn_s_barrier();
        __builtin_amdgcn_sched_barrier(0);

        const short* SA = &sU[s][0];
        const short* SB = &sU[s][4096];
        short8 a[4], b[4];
#pragma unroll
        for (int m = 0; m < 4; m++) {
            int row = wm * 64 + m * 16 + r16;
            a[m] = *(const short8*)&SA[row * 32 + (g ^ (row & 3)) * 8];
        }
#pragma unroll
        for (int n = 0; n < 4; n++) {
            int row = wn * 64 + n * 16 + r16;
            b[n] = *(const short8*)&SB[row * 32 + (g ^ (row & 3)) * 8];
        }
        __builtin_amdgcn_s_setprio(1);
#pragma unroll
        for (int m = 0; m < 4; m++)
#pragma unroll
            for (int n = 0; n < 4; n++)
                acc[m][n] = __builtin_amdgcn_mfma_f32_16x16x32_bf16(a[m], b[n], acc[m][n], 0, 0, 0);
        __builtin_amdgcn_s_setprio(0);
        __builtin_amdgcn_sched_barrier(0);
        __builtin_amdgcn_s_barrier();
        if (u + 4 < NU) STAGE_UNIT(u + 4, s);
        s = (s == 3) ? 0 : s + 1;
    }
#undef STAGE_UNIT

    size_t rbase = (size_t)tm * 128 + wm * 64 + g * 4;
    size_t cbase = (size_t)tn * 128 + wn * 64 + r16;
#pragma unroll
    for (int m = 0; m < 4; m++)
#pragma unroll
        for (int n = 0; n < 4; n++) {
            size_t col = cbase + n * 16;
            float bv = bias ? bias[col] : 0.f;
#pragma unroll
            for (int r = 0; r < 4; r++) {
                size_t row = rbase + m * 16 + r;
                float val = acc[m][n][r] + bv;
                if (MODE == 0) {
                    ((unsigned short*)Cv)[row * ldc + col] = f2bf(val);
                } else if (MODE == 1) {
                    float gv = val / (1.f + __expf(-1.702f * val));
                    ((unsigned short*)Cv)[row * ldc + col] = f2bf(gv);
                } else {
                    ((float*)Cv)[row * ldc + col] += val;
                }
            }
        }
}

// ---------------- attention: per-seq block (512 thr = 8 waves = 8 heads) ------
__global__ __launch_bounds__(512) void k_attn(const unsigned short* __restrict__ Qm,
                                              const unsigned short* __restrict__ KVm,
                                              unsigned short* __restrict__ Om) {
    __shared__ __align__(16) short sAll[3 * 17 * 520];
    __shared__ float sP[8 * 17 * 17];
    int seq = blockIdx.x;
    size_t tb = (size_t)seq * 17;
    for (int c = threadIdx.x; c < 3264; c += 512) {
        int mat = c / 1088, rem = c % 1088, row = rem >> 6, ch = rem & 63;
        const short8* src;
        if (mat == 0)
            src = (const short8*)(Qm + (tb + row) * 512 + ch * 8);
        else if (mat == 1)
            src = (const short8*)(KVm + (tb + row) * 1024 + ch * 8);
        else
            src = (const short8*)(KVm + (tb + row) * 1024 + 512 + ch * 8);
        *(short8*)&sAll[mat * (17 * 520) + row * 520 + ch * 8] = *src;
    }
    __syncthreads();
    int h = threadIdx.x >> 6, lane = threadIdx.x & 63;
    const short* sQ = sAll;
    const short* sK = sAll + 17 * 520;
    const short* sV = sAll + 2 * 17 * 520;
    int jj = lane < 17 ? lane : 0;
    for (int i = 0; i < 17; i++) {
        float acc = 0.f;
#pragma unroll
        for (int c = 0; c < 8; c++) {
            short8 q8 = *(const short8*)&sQ[i * 520 + h * 64 + c * 8];
            short8 k8 = *(const short8*)&sK[jj * 520 + h * 64 + c * 8];
#pragma unroll
            for (int e = 0; e < 8; e++) acc += bf2f(q8[e]) * bf2f(k8[e]);
        }
        float sc = (lane < 17) ? acc * 0.125f : -1e30f;
        float m = sc;
#pragma unroll
        for (int off = 32; off; off >>= 1) m = fmaxf(m, __shfl_xor(m, off));
        float p = (lane < 17) ? __expf(sc - m) : 0.f;
        float sum = p;
#pragma unroll
        for (int off = 32; off; off >>= 1) sum += __shfl_xor(sum, off);
        if (lane < 17) sP[(h * 17 + i) * 17 + lane] = p / sum;
    }
    for (int i = 0; i < 17; i++) {
        float o = 0.f;
#pragma unroll
        for (int t = 0; t < 17; t++)
            o += sP[(h * 17 + i) * 17 + t] * bf2f(sV[t * 520 + h * 64 + lane]);
        Om[(tb + i) * 512 + h * 64 + lane] = f2bf(o);
    }
}

// ---------------------------------------------------------------------------
extern "C" void kernel_launch(void* const* d_in, const int* in_sizes, int n_in,
                              void* d_out, int out_size, void* d_ws, size_t ws_size,
                              hipStream_t stream) {
    const float* image_feature = (const float*)d_in[0];
    const float* image_tokens = (const float*)d_in[1];
    const float* text_feature = (const float*)d_in[2];
    const float* text_tokens = (const float*)d_in[3];
    const int* atte_mask = (const int*)d_in[4];
    const float* img_cls = (const float*)d_in[5];
    const float* txt_cls = (const float*)d_in[6];
    const float* in_proj_w = (const float*)d_in[7];
    const float* in_proj_b = (const float*)d_in[8];
    const float* out_w = (const float*)d_in[9];
    const float* out_b = (const float*)d_in[10];
    const float* ln1_w = (const float*)d_in[11];
    const float* ln1_b = (const float*)d_in[12];
    const float* ln2_w = (const float*)d_in[13];
    const float* ln2_b = (const float*)d_in[14];
    const float* ln3_w = (const float*)d_in[15];
    const float* ln3_b = (const float*)d_in[16];
    const float* fc_w = (const float*)d_in[17];
    const float* fc_b = (const float*)d_in[18];
    const float* proj_w = (const float*)d_in[19];
    const float* proj_b = (const float*)d_in[20];

    // ---- workspace layout (adaptive; see round-2 notes) ----
    char* ws = (char*)d_ws;
    const size_t OFF_K = 12582912;
    const size_t OFF_CH = OFF_K + 35651584;  // 48,234,496
    size_t avail = ws_size > OFF_CH ? ws_size - OFF_CH : 0;
    int C = 2048;  // seqs per chunk
    while (C > 256 && (size_t)87040 * C > avail) C >>= 1;
    int nch = 2048 / C;

    unsigned short* wbf = (unsigned short*)ws;
    unsigned short* w_inproj = wbf;                // 2*1536*512 elems
    unsigned short* w_outp = wbf + 1572864;        // 2*512*512
    unsigned short* w_fc = wbf + 2097152;          // 2*2048*512
    unsigned short* w_proj = wbf + 4194304;        // 2*512*2048
    unsigned short* kstream = (unsigned short*)(ws + OFF_K);
    char* chreg = ws + OFF_CH;
    // early overlay
    float* img_n = (float*)(chreg + 0);            // 12,845,056
    float* txt_n = (float*)(chreg + 12845056);     //  5,046,272
    float* isum = (float*)(chreg + 17891328);      //     65,536
    float* tmask = (float*)(chreg + 17956864);     //     65,536
    float* simg = (float*)(chreg + 18022400);      //    802,816
    float* stxt = (float*)(chreg + 18825216);      //    315,392
    int* idx_i = (int*)(chreg + 19140608);         //     65,536
    int* idx_t = (int*)(chreg + 19206144);         //     65,536
    // chunk-time pointers
    unsigned short* qn = (unsigned short*)chreg;                      // 17408*C B
    unsigned short* qkvQ = (unsigned short*)(chreg + (size_t)17408 * C);
    unsigned short* qkvKV = (unsigned short*)(chreg + (size_t)34816 * C);
    unsigned short* atto = (unsigned short*)(chreg + (size_t)69632 * C);
    unsigned short* hbuf = qkvQ;  // 69632*C B, overlays qkvQ+qkvKV+atto
    float* q = (float*)d_out;

    // weights -> bf16
    k_f2b<<<1024, 256, 0, stream>>>(in_proj_w, w_inproj, 1572864);
    k_f2b<<<1024, 256, 0, stream>>>(out_w, w_outp, 524288);
    k_f2b<<<1024, 256, 0, stream>>>(fc_w, w_fc, 2097152);
    k_f2b<<<1024, 256, 0, stream>>>(proj_w, w_proj, 2097152);

    // token normalize
    k_l2norm<<<6272, 256, 0, stream>>>(image_tokens, img_n);
    k_l2norm<<<2464, 256, 0, stream>>>(text_tokens, txt_n);

    // factored score vectors
    k_colsum<<<32, 512, 0, stream>>>(img_n, nullptr, isum, 196);
    k_colsum<<<32, 512, 0, stream>>>(txt_n, atte_mask, tmask, 77);

    // scores + top-k + gather (q -> d_out f32, k -> bf16)
    k_scores<<<1024, 256, 0, stream>>>(img_n, tmask, simg, 196, 0);
    k_scores<<<1024, 256, 0, stream>>>(txt_n, isum, stxt, 77, 1);
    k_topk<<<2048, 64, 0, stream>>>(simg, stxt, idx_i, idx_t);
    k_gather<<<69632, 128, 0, stream>>>(img_n, txt_n, image_feature, text_feature,
                                        img_cls, txt_cls, idx_i, idx_t, q, kstream);

    // 2-layer cross-attention transformer, chunked over sequences
    for (int ch = 0; ch < nch; ch++) {
        size_t r0 = (size_t)ch * C * 17;
        float* qc = q + r0 * 512;
        const unsigned short* kc = kstream + r0 * 512;
        int rowsC = 17 * C;
        int gmt = rowsC / 128;  // M-tiles
        for (int l = 0; l < 2; l++) {
            const unsigned short* Wq = w_inproj + (size_t)l * 786432;
            const unsigned short* Wkv = Wq + 262144;
            const float* bq = in_proj_b + l * 1536;
            const float* bkv = bq + 512;
            k_ln<0><<<rowsC, 256, 0, stream>>>(qc, ln1_w + l * 512, ln1_b + l * 512, qn);
            k_gemm<0><<<gmt * 4, 256, 0, stream>>>(qn, Wq, bq, qkvQ, 512, 512, 4);
            k_ln<1><<<rowsC, 256, 0, stream>>>(kc, ln2_w + l * 512, ln2_b + l * 512, qn);
            k_gemm<0><<<gmt * 8, 256, 0, stream>>>(qn, Wkv, bkv, qkvKV, 512, 1024, 8);
            k_attn<<<C, 512, 0, stream>>>(qkvQ, qkvKV, atto);
            k_gemm<2><<<gmt * 4, 256, 0, stream>>>(atto, w_outp + (size_t)l * 262144,
                                                   out_b + l * 512, qc, 512, 512, 4);
            k_ln<0><<<rowsC, 256, 0, stream>>>(qc, ln3_w + l * 512, ln3_b + l * 512, qn);
            k_gemm<1><<<gmt * 16, 256, 0, stream>>>(qn, w_fc + (size_t)l * 1048576,
                                                    fc_b + l * 2048, hbuf, 512, 2048, 16);
            k_gemm<2><<<gmt * 4, 256, 0, stream>>>(hbuf, w_proj + (size_t)l * 1048576,
                                                   proj_b + l * 512, qc, 2048, 512, 4);
        }
    }
}